// Round 14
// baseline (5247.466 us; speedup 1.0000x reference)
//
#include <hip/hip_runtime.h>
#include <cstdio>

// ============================================================================
// ROUND 14: all tensors are FP32 (proven by R13 entry dump: f1/f2 read as
// fp32 give plausible normals, gamma reads as 1.0f; as bf16 they're garbage).
// Rounds 0-13 wrote bf16 into a 16MB fp32 output buffer — upper half stayed
// zero, absmax pinned at max|ref|=11.1875. This round: fp32 end-to-end.
// ============================================================================

// Keeps the harness-stub identifier name (unused utility).
__global__ __launch_bounds__(256) void CrossModalityPositionAttention_56556129354448_kernel(
    float* dst, float val, int n)
{
  const int i = blockIdx.x * 256 + threadIdx.x;
  if (i < n) dst[i] = val;
}

// ---------------------------------------------------------------------------
// Conv3x3(pad=1) + folded BN + ReLU.  Cin=256 -> Cout=64.  All fp32.
// in: NCHW [4][256][64][64].  out: [4][64][4096] (NCHW).
// grid (16, 64, 4): x = y-row group (4 rows), y = co, z = b.  block 256.
__global__ __launch_bounds__(256) void conv1_f32(
    const float* __restrict__ in, const float* __restrict__ w,
    const float* __restrict__ bi, const float* __restrict__ g,
    const float* __restrict__ be, const float* __restrict__ mu,
    const float* __restrict__ va, float* __restrict__ out)
{
  const int b = blockIdx.z;
  const int co = blockIdx.y;
  const int y = blockIdx.x * 4 + (threadIdx.x >> 6);
  const int x = threadIdx.x & 63;

  float acc = 0.f;
  const float* inb = in + (size_t)(b * 256) * 4096;
  const float* wco = w + (size_t)co * 256 * 9;
  for (int ci = 0; ci < 256; ++ci) {
    const float* ip = inb + (size_t)ci * 4096;
    const float* wp = wco + ci * 9;
    #pragma unroll
    for (int ky = 0; ky < 3; ++ky) {
      const int yy = y + ky - 1;
      if (yy < 0 || yy > 63) continue;
      #pragma unroll
      for (int kx = 0; kx < 3; ++kx) {
        const int xx = x + kx - 1;
        if (xx < 0 || xx > 63) continue;
        acc += ip[yy * 64 + xx] * wp[ky * 3 + kx];
      }
    }
  }
  // BN fold: y = (conv + b)*inv + (beta - mean*inv), inv = gamma*rsqrt(var+eps)
  const float inv = g[co] * rsqrtf(va[co] + 1e-5f);
  float r = (acc + bi[co]) * inv + be[co] - mu[co] * inv;
  r = fmaxf(r, 0.f);
  out[((size_t)b * 64 + co) * 4096 + y * 64 + x] = r;
}

// ---------------------------------------------------------------------------
// Attention for one query position n: s[m] = sum_c q[c,n] k[c,m];
// softmax over m (exact two-pass fp32); o[c] = sum_m p[m] v[c,m].
// q,k,v,f all [4][64][4096] fp32.  grid (4096, 4): x = n, y = b.  block 256.
__global__ __launch_bounds__(256) void attention_f32(
    const float* __restrict__ q, const float* __restrict__ k,
    const float* __restrict__ v, float* __restrict__ f)
{
  const int b = blockIdx.y;
  const int n = blockIdx.x;
  const int t = threadIdx.x;

  __shared__ float qrow[64];
  __shared__ float s[4096];
  __shared__ float red[256];
  __shared__ float o_lds[4][64];

  if (t < 64) qrow[t] = q[((size_t)b * 64 + t) * 4096 + n];
  __syncthreads();

  const float* kb = k + (size_t)(b * 64) * 4096;
  float lmax = -1e30f;
  for (int j = 0; j < 16; ++j) {
    const int m = t + j * 256;
    float acc = 0.f;
    #pragma unroll 8
    for (int c = 0; c < 64; ++c) acc += qrow[c] * kb[(size_t)c * 4096 + m];
    s[m] = acc;
    lmax = fmaxf(lmax, acc);
  }
  red[t] = lmax;
  __syncthreads();
  for (int st = 128; st > 0; st >>= 1) {
    if (t < st) red[t] = fmaxf(red[t], red[t + st]);
    __syncthreads();
  }
  const float mx = red[0];
  __syncthreads();

  float lsum = 0.f;
  for (int j = 0; j < 16; ++j) {
    const int m = t + j * 256;
    const float p = __expf(s[m] - mx);
    s[m] = p;
    lsum += p;
  }
  red[t] = lsum;
  __syncthreads();
  for (int st = 128; st > 0; st >>= 1) {
    if (t < st) red[t] = red[t] + red[t + st];
    __syncthreads();
  }
  const float invl = 1.f / red[0];
  __syncthreads();

  // o[c] = sum_m p[m] * v[c][m]; thread t covers c = t&63, m-quarter = t>>6.
  const int c = t & 63;
  const int part = t >> 6;
  const float* vp = v + ((size_t)b * 64 + c) * 4096 + part * 1024;
  const float* sp = s + part * 1024;
  float acc = 0.f;
  #pragma unroll 8
  for (int i = 0; i < 1024; ++i) acc += sp[i] * vp[i];
  o_lds[part][c] = acc;
  __syncthreads();
  if (t < 64) {
    const float o = (o_lds[0][t] + o_lds[1][t] + o_lds[2][t] + o_lds[3][t]) * invl;
    f[((size_t)b * 64 + t) * 4096 + n] = o;
  }
}

// ---------------------------------------------------------------------------
// Conv3x3(pad=1) + folded BN + ReLU + residual.  Cin=64 -> Cout=256.  fp32.
// fin: [4][64][4096].  res/out: NCHW [4][256][64][64].
// grid (16, 256, 4): x = y-row group, y = co, z = b.  block 256.
__global__ __launch_bounds__(256) void conv_r_f32(
    const float* __restrict__ fin, const float* __restrict__ w,
    const float* __restrict__ bi, const float* __restrict__ g,
    const float* __restrict__ be, const float* __restrict__ mu,
    const float* __restrict__ va, const float* __restrict__ res,
    float* __restrict__ out)
{
  const int b = blockIdx.z;
  const int co = blockIdx.y;
  const int y = blockIdx.x * 4 + (threadIdx.x >> 6);
  const int x = threadIdx.x & 63;

  float acc = 0.f;
  const float* inb = fin + (size_t)(b * 64) * 4096;
  const float* wco = w + (size_t)co * 64 * 9;
  for (int ci = 0; ci < 64; ++ci) {
    const float* ip = inb + (size_t)ci * 4096;
    const float* wp = wco + ci * 9;
    #pragma unroll
    for (int ky = 0; ky < 3; ++ky) {
      const int yy = y + ky - 1;
      if (yy < 0 || yy > 63) continue;
      #pragma unroll
      for (int kx = 0; kx < 3; ++kx) {
        const int xx = x + kx - 1;
        if (xx < 0 || xx > 63) continue;
        acc += ip[yy * 64 + xx] * wp[ky * 3 + kx];
      }
    }
  }
  const float inv = g[co] * rsqrtf(va[co] + 1e-5f);
  float r = (acc + bi[co]) * inv + be[co] - mu[co] * inv;
  r = fmaxf(r, 0.f);
  const size_t idx = ((size_t)b * 256 + co) * 4096 + y * 64 + x;
  out[idx] = res[idx] + r;
}

// ---------------------------------------------------------------------------
extern "C" void kernel_launch(void* const* d_in, const int* in_sizes, int n_in,
                              void* d_out, int out_size, void* d_ws, size_t ws_size,
                              hipStream_t stream) {
  const float* f1 = (const float*)d_in[0];
  const float* f2 = (const float*)d_in[1];
  const float* qw = (const float*)d_in[2];  const float* qb = (const float*)d_in[3];
  const float* qg = (const float*)d_in[4];  const float* qbe = (const float*)d_in[5];
  const float* qm = (const float*)d_in[6];  const float* qv = (const float*)d_in[7];
  const float* kw = (const float*)d_in[8];  const float* kb = (const float*)d_in[9];
  const float* kg = (const float*)d_in[10]; const float* kbe = (const float*)d_in[11];
  const float* km = (const float*)d_in[12]; const float* kv = (const float*)d_in[13];
  const float* vw = (const float*)d_in[14]; const float* vb = (const float*)d_in[15];
  const float* vg = (const float*)d_in[16]; const float* vbe = (const float*)d_in[17];
  const float* vm = (const float*)d_in[18]; const float* vv = (const float*)d_in[19];
  const float* rw = (const float*)d_in[20]; const float* rb = (const float*)d_in[21];
  const float* rg = (const float*)d_in[22]; const float* rbe = (const float*)d_in[23];
  const float* rm = (const float*)d_in[24]; const float* rv = (const float*)d_in[25];

  hipStreamCaptureStatus cap = hipStreamCaptureStatusNone;
  unsigned long long capid = 0;
  const hipError_t ce = hipStreamGetCaptureInfo(stream, &cap, &capid);
  const bool capturing = (ce == hipSuccess) && (cap != hipStreamCaptureStatusNone);

  // Workspace: q,k,v,f fp32 [4][64][4096] = 4 MB each (ws_size = 256 MB).
  const size_t SZ1 = (size_t)4 * 64 * 4096 * 4;
  float* qp = (float*)d_ws;
  float* kp = (float*)((char*)d_ws + SZ1);
  float* vp = (float*)((char*)d_ws + 2 * SZ1);
  float* fp = (float*)((char*)d_ws + 3 * SZ1);

  conv1_f32<<<dim3(16, 64, 4), 256, 0, stream>>>(f2, qw, qb, qg, qbe, qm, qv, qp);
  conv1_f32<<<dim3(16, 64, 4), 256, 0, stream>>>(f1, kw, kb, kg, kbe, km, kv, kp);
  conv1_f32<<<dim3(16, 64, 4), 256, 0, stream>>>(f1, vw, vb, vg, vbe, vm, vv, vp);
  attention_f32<<<dim3(4096, 4), 256, 0, stream>>>(qp, kp, vp, fp);
  conv_r_f32<<<dim3(16, 256, 4), 256, 0, stream>>>(fp, rw, rb, rg, rbe, rm, rv,
                                                   f1, (float*)d_out);

  if (!capturing) {
    const hipError_t le = hipGetLastError();
    const hipError_t se = hipStreamSynchronize(stream);
    float h[4] = {0, 0, 0, 0};
    (void)hipMemcpy(h, d_out, 16, hipMemcpyDeviceToHost);
    float hin[2] = {0, 0};
    (void)hipMemcpy(hin, d_in[0], 8, hipMemcpyDeviceToHost);
    fprintf(stderr,
        "ATHENA_R14 fp32 le=%d sync=%d f1=[%g %g] out=[%g %g %g %g]\n",
        (int)le, (int)se, hin[0], hin[1], h[0], h[1], h[2], h[3]);
    fflush(stderr);
  }
}